// Round 3
// baseline (1252.754 us; speedup 1.0000x reference)
//
#include <hip/hip_runtime.h>
#include <hip/hip_bf16.h>
#include <math.h>

#define DM 768
#define DI 1536
#define DSN 16
#define NB 2
#define SL 1024
#define MROWS 2048
#define VOC 50257
#define VOCP 50304
#define EPSR 1e-5f

typedef __attribute__((ext_vector_type(8))) short short8;
typedef __attribute__((ext_vector_type(4))) float f32x4;
typedef unsigned short u16;

__device__ inline u16 f2bf(float f) {
    unsigned u = __builtin_bit_cast(unsigned, f);
    u += 0x7FFFu + ((u >> 16) & 1u);   // round-to-nearest-even
    return (u16)(u >> 16);
}

// ---------------- embedding gather ----------------
__global__ void k_embed(const int* __restrict__ tok, const float* __restrict__ emb,
                        float* __restrict__ x) {
    int r = blockIdx.x;
    int t = tok[r];
    const float* src = emb + (size_t)t * DM;
    float* dst = x + (size_t)r * DM;
    for (int i = threadIdx.x; i < DM; i += 256) dst[i] = src[i];
}

// ---------------- RMSNorm -> bf16 ----------------
__global__ __launch_bounds__(256)
void k_rmsnorm_bf16(const float* __restrict__ x, const float* __restrict__ w,
                    u16* __restrict__ out) {
    int r = blockIdx.x;
    const float* row = x + (size_t)r * DM;
    int c0 = threadIdx.x * 3;
    float v[3]; float ss = 0.f;
#pragma unroll
    for (int i = 0; i < 3; ++i) { v[i] = row[c0 + i]; ss += v[i] * v[i]; }
#pragma unroll
    for (int o = 32; o > 0; o >>= 1) ss += __shfl_down(ss, o);
    __shared__ float s[4];
    int lane = threadIdx.x & 63, wv = threadIdx.x >> 6;
    if (lane == 0) s[wv] = ss;
    __syncthreads();
    float sc = rsqrtf((s[0] + s[1] + s[2] + s[3]) / (float)DM + EPSR);
#pragma unroll
    for (int i = 0; i < 3; ++i)
        out[(size_t)r * DM + c0 + i] = f2bf(v[i] * sc * w[c0 + i]);
}

// ---------------- f32 -> bf16 with 2D pad (rows/cols), src leading dim sld ----------------
__global__ void k_cvt_pad(const float* __restrict__ src, u16* __restrict__ dst,
                          int sr, int sc, int sld, int dc, long total) {
    long i = (long)blockIdx.x * 256 + threadIdx.x;
    if (i >= total) return;
    int r = (int)(i / dc), c = (int)(i % dc);
    float v = (r < sr && c < sc) ? src[(size_t)r * sld + c] : 0.f;
    dst[i] = f2bf(v);
}

// ---------------- causal depthwise conv (width 4) + bias + silu ----------------
__global__ void k_conv_silu(const float* __restrict__ xz, const float* __restrict__ cw,
                            const float* __restrict__ cb, float* __restrict__ uc,
                            u16* __restrict__ ucb) {
    int d = blockIdx.x * 256 + threadIdx.x;   // 0..1535
    int r = blockIdx.y;                       // 0..2047
    int l = r & (SL - 1);
    float acc = cb[d];
#pragma unroll
    for (int j = 0; j < 4; ++j) {
        int ls = l - 3 + j;
        if (ls >= 0) acc += xz[(size_t)(r - 3 + j) * (2 * DI) + d] * cw[d * 4 + j];
    }
    float s = acc / (1.f + __expf(-acc));
    uc[(size_t)r * DI + d] = s;
    ucb[(size_t)r * DI + d] = f2bf(s);
}

// ---------------- softplus(dt + b) ----------------
__global__ void k_softplus(const float* __restrict__ in, const float* __restrict__ b,
                           float* __restrict__ out) {
    int i = blockIdx.x * 256 + threadIdx.x;   // 2048*1536
    int d = i % DI;
    float v = in[i] + b[d];
    out[i] = (v > 20.f) ? v : log1pf(__expf(v));
}

// ---------------- selective scan + D-skip + silu(z) gate -> bf16 ----------------
__global__ __launch_bounds__(256)
void k_scan(const float* __restrict__ delta, const float* __restrict__ uc,
            const float* __restrict__ xdbl, const float* __restrict__ xz,
            const float* __restrict__ alog, const float* __restrict__ Dp,
            u16* __restrict__ ybf) {
    int b  = blockIdx.x / 96;
    int d0 = (blockIdx.x % 96) * 16;
    int tid = threadIdx.x, n = tid & 15, ch = tid >> 4;
    int d = d0 + ch;
    float A  = -__expf(alog[d * DSN + n]);
    float Dv = Dp[d];
    __shared__ float ds_[32][16], us_[32][16], bs_[32][16], cs_[32][16], zs_[32][16];
    float h = 0.f;
    for (int t0 = 0; t0 < SL; t0 += 32) {
        __syncthreads();
#pragma unroll
        for (int e = 0; e < 2; ++e) {
            int lin = e * 256 + tid; int tt = lin >> 4; int cc = lin & 15;
            size_t row = (size_t)(b * SL + t0 + tt);
            ds_[tt][cc] = delta[row * DI + d0 + cc];
            us_[tt][cc] = uc[row * DI + d0 + cc];
            zs_[tt][cc] = xz[row * (2 * DI) + DI + d0 + cc];
            bs_[tt][cc] = xdbl[row * 128 + 48 + cc];
            cs_[tt][cc] = xdbl[row * 128 + 64 + cc];
        }
        __syncthreads();
        for (int tt = 0; tt < 32; ++tt) {
            float dl = ds_[tt][ch];
            float uv = us_[tt][ch];
            float dA = __expf(dl * A);
            h = h * dA + dl * bs_[tt][n] * uv;
            float p = h * cs_[tt][n];
            p += __shfl_xor(p, 1);
            p += __shfl_xor(p, 2);
            p += __shfl_xor(p, 4);
            p += __shfl_xor(p, 8);
            if (n == 0) {
                float y = p + uv * Dv;
                float z = zs_[tt][ch];
                y *= z / (1.f + __expf(-z));
                ybf[(size_t)(b * SL + t0 + tt) * DI + d] = f2bf(y);
            }
        }
    }
}

// ---------------- bf16 MFMA GEMM: C[M,N](f32) = A[M,K](bf16) @ W[N,K]^T(bf16) ----------------
// 128x128 tile, BK=32, 4 waves (2x2 of 64x64), global_load_lds width-16 staging.
template <bool ADD_RES, bool NGUARD>
__global__ __launch_bounds__(256)
void k_gemm_bt(const u16* __restrict__ A, const u16* __restrict__ W,
               float* __restrict__ C, const float* __restrict__ RES,
               int K, int ldc, int nmax) {
    __shared__ u16 Al[128 * 32];
    __shared__ u16 Wl[128 * 32];
    int m0 = blockIdx.y * 128, n0 = blockIdx.x * 128;
    int tid = threadIdx.x, wave = tid >> 6, lane = tid & 63;
    int wm = wave >> 1, wn = wave & 1;
    f32x4 acc[4][4] = {};
    const int rS = (lane >> 2);            // staging row within 16-row chunk
    const int kS = (lane & 3) * 8;         // staging k offset (elements)
    const int kofs = (lane >> 4) * 8;      // fragment k offset
    const int fr = lane & 15;              // fragment row/col

    for (int k0 = 0; k0 < K; k0 += 32) {
#pragma unroll
        for (int i = 0; i < 2; ++i) {
            int rowA = m0 + wave * 32 + i * 16 + rS;
            const u16* ga = A + (size_t)rowA * K + k0 + kS;
            __builtin_amdgcn_global_load_lds(
                (const __attribute__((address_space(1))) void*)ga,
                (__attribute__((address_space(3))) void*)(&Al[wave * 1024 + i * 512]),
                16, 0, 0);
            int rowW = n0 + wave * 32 + i * 16 + rS;
            const u16* gw = W + (size_t)rowW * K + k0 + kS;
            __builtin_amdgcn_global_load_lds(
                (const __attribute__((address_space(1))) void*)gw,
                (__attribute__((address_space(3))) void*)(&Wl[wave * 1024 + i * 512]),
                16, 0, 0);
        }
        __syncthreads();
        short8 af[4], bfr[4];
#pragma unroll
        for (int f = 0; f < 4; ++f) {
            af[f]  = *(const short8*)&Al[(wm * 64 + f * 16 + fr) * 32 + kofs];
            bfr[f] = *(const short8*)&Wl[(wn * 64 + f * 16 + fr) * 32 + kofs];
        }
#pragma unroll
        for (int i = 0; i < 4; ++i)
#pragma unroll
            for (int j = 0; j < 4; ++j)
                acc[i][j] = __builtin_amdgcn_mfma_f32_16x16x32_bf16(af[i], bfr[j], acc[i][j], 0, 0, 0);
        __syncthreads();
    }
    int r4 = (lane >> 4) * 4;
#pragma unroll
    for (int i = 0; i < 4; ++i)
#pragma unroll
        for (int j = 0; j < 4; ++j)
#pragma unroll
            for (int rr = 0; rr < 4; ++rr) {
                int row = m0 + wm * 64 + i * 16 + r4 + rr;
                int col = n0 + wn * 64 + j * 16 + fr;
                if (!NGUARD || col < nmax) {
                    size_t off = (size_t)row * ldc + col;
                    float v = acc[i][j][rr];
                    if (ADD_RES) v += RES[off];
                    C[off] = v;
                }
            }
}

// ---------------- host ----------------
extern "C" void kernel_launch(void* const* d_in, const int* in_sizes, int n_in,
                              void* d_out, int out_size, void* d_ws, size_t ws_size,
                              hipStream_t stream) {
    (void)in_sizes; (void)n_in; (void)out_size;
    const int*   tok   = (const int*)d_in[0];
    const float* emb   = (const float*)d_in[1];
    const float* normw = (const float*)d_in[2];
    const float* inw   = (const float*)d_in[3];
    const float* cw    = (const float*)d_in[4];
    const float* cb    = (const float*)d_in[5];
    const float* xpw   = (const float*)d_in[6];
    const float* dtw   = (const float*)d_in[7];
    const float* dtb   = (const float*)d_in[8];
    const float* alog  = (const float*)d_in[9];
    const float* Dp    = (const float*)d_in[10];
    const float* outw  = (const float*)d_in[11];
    const float* normf = (const float*)d_in[12];
    const float* lmw   = (const float*)d_in[13];
    float* out = (float*)d_out;

    char* p = (char*)d_ws;
    auto alloc = [&](size_t bytes) { char* r = p; p += (bytes + 255) & ~(size_t)255; return r; };
    float* x     = (float*)alloc((size_t)MROWS * DM * 4);
    u16*   xnb   = (u16*)  alloc((size_t)MROWS * DM * 2);
    float* xz    = (float*)alloc((size_t)MROWS * 2 * DI * 4);
    float* uc    = (float*)alloc((size_t)MROWS * DI * 4);
    u16*   ucb   = (u16*)  alloc((size_t)MROWS * DI * 2);
    float* xdbl  = (float*)alloc((size_t)MROWS * 128 * 4);
    u16*   xdblb = (u16*)  alloc((size_t)MROWS * 64 * 2);
    float* dtraw = (float*)alloc((size_t)MROWS * DI * 4);
    float* delta = (float*)alloc((size_t)MROWS * DI * 4);
    u16*   ybf   = (u16*)  alloc((size_t)MROWS * DI * 2);
    u16*   winb  = (u16*)  alloc((size_t)(2 * DI) * DM * 2);
    u16*   wxpb  = (u16*)  alloc((size_t)128 * DI * 2);
    u16*   wdtb  = (u16*)  alloc((size_t)DI * 64 * 2);
    u16*   woutb = (u16*)  alloc((size_t)DM * DI * 2);
    u16*   wlmb  = (u16*)  alloc((size_t)VOCP * DM * 2);
    if ((size_t)(p - (char*)d_ws) > ws_size) return;  // insufficient scratch: fail loudly

    // lm_head weight -> bf16, padded to 50304 rows
    {
        long tot = (long)VOCP * DM;
        k_cvt_pad<<<dim3((unsigned)((tot + 255) / 256)), 256, 0, stream>>>(
            lmw, wlmb, VOC, DM, DM, DM, tot);
    }

    k_embed<<<MROWS, 256, 0, stream>>>(tok, emb, x);

    for (int i = 0; i < NB; ++i) {
        k_rmsnorm_bf16<<<MROWS, 256, 0, stream>>>(x, normw + i * DM, xnb);

        { long tot = (long)(2 * DI) * DM;
          k_cvt_pad<<<dim3((unsigned)((tot + 255) / 256)), 256, 0, stream>>>(
              inw + (size_t)i * 2 * DI * DM, winb, 2 * DI, DM, DM, DM, tot); }
        k_gemm_bt<false, false><<<dim3(2 * DI / 128, MROWS / 128), 256, 0, stream>>>(
            xnb, winb, xz, nullptr, DM, 2 * DI, 2 * DI);

        k_conv_silu<<<dim3(DI / 256, MROWS), 256, 0, stream>>>(
            xz, cw + (size_t)i * DI * 4, cb + (size_t)i * DI, uc, ucb);

        { long tot = (long)128 * DI;
          k_cvt_pad<<<dim3((unsigned)((tot + 255) / 256)), 256, 0, stream>>>(
              xpw + (size_t)i * 80 * DI, wxpb, 80, DI, DI, DI, tot); }
        k_gemm_bt<false, false><<<dim3(1, MROWS / 128), 256, 0, stream>>>(
            ucb, wxpb, xdbl, nullptr, DI, 128, 128);

        { long tot = (long)MROWS * 64;
          k_cvt_pad<<<dim3((unsigned)((tot + 255) / 256)), 256, 0, stream>>>(
              xdbl, xdblb, MROWS, 64, 128, 64, tot); }
        { long tot = (long)DI * 64;
          k_cvt_pad<<<dim3((unsigned)((tot + 255) / 256)), 256, 0, stream>>>(
              dtw + (size_t)i * DI * 48, wdtb, DI, 48, 48, 64, tot); }
        k_gemm_bt<false, false><<<dim3(DI / 128, MROWS / 128), 256, 0, stream>>>(
            xdblb, wdtb, dtraw, nullptr, 64, DI, DI);

        k_softplus<<<dim3(MROWS * DI / 256), 256, 0, stream>>>(dtraw, dtb + i * DI, delta);

        k_scan<<<dim3(NB * (DI / 16)), 256, 0, stream>>>(
            delta, uc, xdbl, xz, alog + (size_t)i * DI * DSN, Dp + i * DI, ybf);

        { long tot = (long)DM * DI;
          k_cvt_pad<<<dim3((unsigned)((tot + 255) / 256)), 256, 0, stream>>>(
              outw + (size_t)i * DM * DI, woutb, DM, DI, DI, DI, tot); }
        k_gemm_bt<true, false><<<dim3(DM / 128, MROWS / 128), 256, 0, stream>>>(
            ybf, woutb, x, x, DI, DM, DM);
    }

    k_rmsnorm_bf16<<<MROWS, 256, 0, stream>>>(x, normf, xnb);
    k_gemm_bt<false, true><<<dim3(VOCP / 128, MROWS / 128), 256, 0, stream>>>(
        xnb, wlmb, out, nullptr, DM, VOC, VOC);
}

// Round 4
// 1251.252 us; speedup vs baseline: 1.0012x; 1.0012x over previous
//
#include <hip/hip_runtime.h>
#include <hip/hip_bf16.h>
#include <math.h>

#define DM 768
#define DI 1536
#define DSN 16
#define NB 2
#define SL 1024
#define MROWS 2048
#define VOC 50257
#define VOCP 50304
#define EPSR 1e-5f

typedef __attribute__((ext_vector_type(8))) short short8;
typedef __attribute__((ext_vector_type(4))) float f32x4;
typedef unsigned short u16;

__device__ inline u16 f2bf(float f) {
    unsigned u = __builtin_bit_cast(unsigned, f);
    u += 0x7FFFu + ((u >> 16) & 1u);   // round-to-nearest-even
    return (u16)(u >> 16);
}

// ---------------- embedding gather ----------------
__global__ void k_embed(const int* __restrict__ tok, const float* __restrict__ emb,
                        float* __restrict__ x) {
    int r = blockIdx.x;
    int t = tok[r];
    const float* src = emb + (size_t)t * DM;
    float* dst = x + (size_t)r * DM;
    for (int i = threadIdx.x; i < DM; i += 256) dst[i] = src[i];
}

// ---------------- RMSNorm -> bf16 ----------------
__global__ __launch_bounds__(256)
void k_rmsnorm_bf16(const float* __restrict__ x, const float* __restrict__ w,
                    u16* __restrict__ out) {
    int r = blockIdx.x;
    const float* row = x + (size_t)r * DM;
    int c0 = threadIdx.x * 3;
    float v[3]; float ss = 0.f;
#pragma unroll
    for (int i = 0; i < 3; ++i) { v[i] = row[c0 + i]; ss += v[i] * v[i]; }
#pragma unroll
    for (int o = 32; o > 0; o >>= 1) ss += __shfl_down(ss, o);
    __shared__ float s[4];
    int lane = threadIdx.x & 63, wv = threadIdx.x >> 6;
    if (lane == 0) s[wv] = ss;
    __syncthreads();
    float sc = rsqrtf((s[0] + s[1] + s[2] + s[3]) / (float)DM + EPSR);
#pragma unroll
    for (int i = 0; i < 3; ++i)
        out[(size_t)r * DM + c0 + i] = f2bf(v[i] * sc * w[c0 + i]);
}

// ---------------- f32 -> bf16 with 2D pad (rows/cols), src leading dim sld ----------------
__global__ void k_cvt_pad(const float* __restrict__ src, u16* __restrict__ dst,
                          int sr, int sc, int sld, int dc, long total) {
    long i = (long)blockIdx.x * 256 + threadIdx.x;
    if (i >= total) return;
    int r = (int)(i / dc), c = (int)(i % dc);
    float v = (r < sr && c < sc) ? src[(size_t)r * sld + c] : 0.f;
    dst[i] = f2bf(v);
}

// ---------------- causal depthwise conv (width 4) + bias + silu ----------------
__global__ void k_conv_silu(const float* __restrict__ xz, const float* __restrict__ cw,
                            const float* __restrict__ cb, float* __restrict__ uc,
                            u16* __restrict__ ucb) {
    int d = blockIdx.x * 256 + threadIdx.x;   // 0..1535
    int r = blockIdx.y;                       // 0..2047
    int l = r & (SL - 1);
    float acc = cb[d];
#pragma unroll
    for (int j = 0; j < 4; ++j) {
        int ls = l - 3 + j;
        if (ls >= 0) acc += xz[(size_t)(r - 3 + j) * (2 * DI) + d] * cw[d * 4 + j];
    }
    float s = acc / (1.f + __expf(-acc));
    uc[(size_t)r * DI + d] = s;
    ucb[(size_t)r * DI + d] = f2bf(s);
}

// ---------------- softplus(dt + b) ----------------
__global__ void k_softplus(const float* __restrict__ in, const float* __restrict__ b,
                           float* __restrict__ out) {
    int i = blockIdx.x * 256 + threadIdx.x;   // 2048*1536
    int d = i % DI;
    float v = in[i] + b[d];
    out[i] = (v > 20.f) ? v : log1pf(__expf(v));
}

// ---------------- selective scan + D-skip + silu(z) gate -> bf16 ----------------
__global__ __launch_bounds__(256)
void k_scan(const float* __restrict__ delta, const float* __restrict__ uc,
            const float* __restrict__ xdbl, const float* __restrict__ xz,
            const float* __restrict__ alog, const float* __restrict__ Dp,
            u16* __restrict__ ybf) {
    int b  = blockIdx.x / 96;
    int d0 = (blockIdx.x % 96) * 16;
    int tid = threadIdx.x, n = tid & 15, ch = tid >> 4;
    int d = d0 + ch;
    float A  = -__expf(alog[d * DSN + n]);
    float Dv = Dp[d];
    __shared__ float ds_[32][16], us_[32][16], bs_[32][16], cs_[32][16], zs_[32][16];
    float h = 0.f;
    for (int t0 = 0; t0 < SL; t0 += 32) {
        __syncthreads();
#pragma unroll
        for (int e = 0; e < 2; ++e) {
            int lin = e * 256 + tid; int tt = lin >> 4; int cc = lin & 15;
            size_t row = (size_t)(b * SL + t0 + tt);
            ds_[tt][cc] = delta[row * DI + d0 + cc];
            us_[tt][cc] = uc[row * DI + d0 + cc];
            zs_[tt][cc] = xz[row * (2 * DI) + DI + d0 + cc];
            bs_[tt][cc] = xdbl[row * 128 + 48 + cc];
            cs_[tt][cc] = xdbl[row * 128 + 64 + cc];
        }
        __syncthreads();
        for (int tt = 0; tt < 32; ++tt) {
            float dl = ds_[tt][ch];
            float uv = us_[tt][ch];
            float dA = __expf(dl * A);
            h = h * dA + dl * bs_[tt][n] * uv;
            float p = h * cs_[tt][n];
            p += __shfl_xor(p, 1);
            p += __shfl_xor(p, 2);
            p += __shfl_xor(p, 4);
            p += __shfl_xor(p, 8);
            if (n == 0) {
                float y = p + uv * Dv;
                float z = zs_[tt][ch];
                y *= z / (1.f + __expf(-z));
                ybf[(size_t)(b * SL + t0 + tt) * DI + d] = f2bf(y);
            }
        }
    }
}

// ---------------- bf16 MFMA GEMM: C[M,N](f32) = A[M,K](bf16) @ W[N,K]^T(bf16) ----------------
// 128x128 tile, BK=32, 4 waves (2x2 of 64x64), global_load_lds width-16 staging.
template <bool ADD_RES, bool NGUARD>
__global__ __launch_bounds__(256)
void k_gemm_bt(const u16* __restrict__ A, const u16* __restrict__ W,
               float* __restrict__ C, const float* __restrict__ RES,
               int K, int ldc, int nmax) {
    __shared__ u16 Al[128 * 32];
    __shared__ u16 Wl[128 * 32];
    int m0 = blockIdx.y * 128, n0 = blockIdx.x * 128;
    int tid = threadIdx.x, wave = tid >> 6, lane = tid & 63;
    int wm = wave >> 1, wn = wave & 1;
    f32x4 acc[4][4] = {};
    const int rS = (lane >> 2);            // staging row within 16-row chunk
    const int kS = (lane & 3) * 8;         // staging k offset (elements)
    const int kofs = (lane >> 4) * 8;      // fragment k offset
    const int fr = lane & 15;              // fragment row/col

    for (int k0 = 0; k0 < K; k0 += 32) {
#pragma unroll
        for (int i = 0; i < 2; ++i) {
            int rowA = m0 + wave * 32 + i * 16 + rS;
            const u16* ga = A + (size_t)rowA * K + k0 + kS;
            __builtin_amdgcn_global_load_lds(
                (const __attribute__((address_space(1))) void*)ga,
                (__attribute__((address_space(3))) void*)(&Al[wave * 1024 + i * 512]),
                16, 0, 0);
            int rowW = n0 + wave * 32 + i * 16 + rS;
            const u16* gw = W + (size_t)rowW * K + k0 + kS;
            __builtin_amdgcn_global_load_lds(
                (const __attribute__((address_space(1))) void*)gw,
                (__attribute__((address_space(3))) void*)(&Wl[wave * 1024 + i * 512]),
                16, 0, 0);
        }
        __syncthreads();
        short8 af[4], bfr[4];
#pragma unroll
        for (int f = 0; f < 4; ++f) {
            af[f]  = *(const short8*)&Al[(wm * 64 + f * 16 + fr) * 32 + kofs];
            bfr[f] = *(const short8*)&Wl[(wn * 64 + f * 16 + fr) * 32 + kofs];
        }
#pragma unroll
        for (int i = 0; i < 4; ++i)
#pragma unroll
            for (int j = 0; j < 4; ++j)
                acc[i][j] = __builtin_amdgcn_mfma_f32_16x16x32_bf16(af[i], bfr[j], acc[i][j], 0, 0, 0);
        __syncthreads();
    }
    int r4 = (lane >> 4) * 4;
#pragma unroll
    for (int i = 0; i < 4; ++i)
#pragma unroll
        for (int j = 0; j < 4; ++j)
#pragma unroll
            for (int rr = 0; rr < 4; ++rr) {
                int row = m0 + wm * 64 + i * 16 + r4 + rr;
                int col = n0 + wn * 64 + j * 16 + fr;
                if (!NGUARD || col < nmax) {
                    size_t off = (size_t)row * ldc + col;
                    float v = acc[i][j][rr];
                    if (ADD_RES) v += RES[off];
                    C[off] = v;
                }
            }
}

// ---------------- host ----------------
extern "C" void kernel_launch(void* const* d_in, const int* in_sizes, int n_in,
                              void* d_out, int out_size, void* d_ws, size_t ws_size,
                              hipStream_t stream) {
    (void)in_sizes; (void)n_in; (void)out_size;
    const int*   tok   = (const int*)d_in[0];
    const float* emb   = (const float*)d_in[1];
    const float* normw = (const float*)d_in[2];
    const float* inw   = (const float*)d_in[3];
    const float* cw    = (const float*)d_in[4];
    const float* cb    = (const float*)d_in[5];
    const float* xpw   = (const float*)d_in[6];
    const float* dtw   = (const float*)d_in[7];
    const float* dtb   = (const float*)d_in[8];
    const float* alog  = (const float*)d_in[9];
    const float* Dp    = (const float*)d_in[10];
    const float* outw  = (const float*)d_in[11];
    const float* normf = (const float*)d_in[12];
    const float* lmw   = (const float*)d_in[13];
    float* out = (float*)d_out;

    char* p = (char*)d_ws;
    auto alloc = [&](size_t bytes) { char* r = p; p += (bytes + 255) & ~(size_t)255; return r; };
    float* x     = (float*)alloc((size_t)MROWS * DM * 4);
    u16*   xnb   = (u16*)  alloc((size_t)MROWS * DM * 2);
    float* xz    = (float*)alloc((size_t)MROWS * 2 * DI * 4);
    float* uc    = (float*)alloc((size_t)MROWS * DI * 4);
    u16*   ucb   = (u16*)  alloc((size_t)MROWS * DI * 2);
    float* xdbl  = (float*)alloc((size_t)MROWS * 128 * 4);
    u16*   xdblb = (u16*)  alloc((size_t)MROWS * 64 * 2);
    float* dtraw = (float*)alloc((size_t)MROWS * DI * 4);
    float* delta = (float*)alloc((size_t)MROWS * DI * 4);
    u16*   ybf   = (u16*)  alloc((size_t)MROWS * DI * 2);
    u16*   winb  = (u16*)  alloc((size_t)(2 * DI) * DM * 2);
    u16*   wxpb  = (u16*)  alloc((size_t)128 * DI * 2);
    u16*   wdtb  = (u16*)  alloc((size_t)DI * 64 * 2);
    u16*   woutb = (u16*)  alloc((size_t)DM * DI * 2);
    u16*   wlmb  = (u16*)  alloc((size_t)VOCP * DM * 2);
    if ((size_t)(p - (char*)d_ws) > ws_size) return;  // insufficient scratch: fail loudly

    // lm_head weight -> bf16, padded to 50304 rows
    {
        long tot = (long)VOCP * DM;
        k_cvt_pad<<<dim3((unsigned)((tot + 255) / 256)), 256, 0, stream>>>(
            lmw, wlmb, VOC, DM, DM, DM, tot);
    }

    k_embed<<<MROWS, 256, 0, stream>>>(tok, emb, x);

    for (int i = 0; i < NB; ++i) {
        k_rmsnorm_bf16<<<MROWS, 256, 0, stream>>>(x, normw + i * DM, xnb);

        { long tot = (long)(2 * DI) * DM;
          k_cvt_pad<<<dim3((unsigned)((tot + 255) / 256)), 256, 0, stream>>>(
              inw + (size_t)i * 2 * DI * DM, winb, 2 * DI, DM, DM, DM, tot); }
        k_gemm_bt<false, false><<<dim3(2 * DI / 128, MROWS / 128), 256, 0, stream>>>(
            xnb, winb, xz, nullptr, DM, 2 * DI, 2 * DI);

        k_conv_silu<<<dim3(DI / 256, MROWS), 256, 0, stream>>>(
            xz, cw + (size_t)i * DI * 4, cb + (size_t)i * DI, uc, ucb);

        { long tot = (long)128 * DI;
          k_cvt_pad<<<dim3((unsigned)((tot + 255) / 256)), 256, 0, stream>>>(
              xpw + (size_t)i * 80 * DI, wxpb, 80, DI, DI, DI, tot); }
        k_gemm_bt<false, false><<<dim3(1, MROWS / 128), 256, 0, stream>>>(
            ucb, wxpb, xdbl, nullptr, DI, 128, 128);

        { long tot = (long)MROWS * 64;
          k_cvt_pad<<<dim3((unsigned)((tot + 255) / 256)), 256, 0, stream>>>(
              xdbl, xdblb, MROWS, 64, 128, 64, tot); }
        { long tot = (long)DI * 64;
          k_cvt_pad<<<dim3((unsigned)((tot + 255) / 256)), 256, 0, stream>>>(
              dtw + (size_t)i * DI * 48, wdtb, DI, 48, 48, 64, tot); }
        k_gemm_bt<false, false><<<dim3(DI / 128, MROWS / 128), 256, 0, stream>>>(
            xdblb, wdtb, dtraw, nullptr, 64, DI, DI);

        k_softplus<<<dim3(MROWS * DI / 256), 256, 0, stream>>>(dtraw, dtb + i * DI, delta);

        k_scan<<<dim3(NB * (DI / 16)), 256, 0, stream>>>(
            delta, uc, xdbl, xz, alog + (size_t)i * DI * DSN, Dp + i * DI, ybf);

        { long tot = (long)DM * DI;
          k_cvt_pad<<<dim3((unsigned)((tot + 255) / 256)), 256, 0, stream>>>(
              outw + (size_t)i * DM * DI, woutb, DM, DI, DI, DI, tot); }
        k_gemm_bt<true, false><<<dim3(DM / 128, MROWS / 128), 256, 0, stream>>>(
            ybf, woutb, x, x, DI, DM, DM);
    }

    k_rmsnorm_bf16<<<MROWS, 256, 0, stream>>>(x, normf, xnb);
    k_gemm_bt<false, true><<<dim3(VOCP / 128, MROWS / 128), 256, 0, stream>>>(
        xnb, wlmb, out, nullptr, DM, VOC, VOC);
}

// Round 5
// 837.932 us; speedup vs baseline: 1.4951x; 1.4933x over previous
//
#include <hip/hip_runtime.h>
#include <hip/hip_bf16.h>
#include <math.h>

#define DM 768
#define DI 1536
#define DSN 16
#define NB 2
#define SL 1024
#define MROWS 2048
#define VOC 50257
#define VOCP 50304
#define EPSR 1e-5f

typedef __attribute__((ext_vector_type(8))) short short8;
typedef __attribute__((ext_vector_type(4))) float f32x4;
typedef __attribute__((ext_vector_type(4))) unsigned short us4;
typedef unsigned short u16;

__device__ inline u16 f2bf(float f) {
    unsigned u = __builtin_bit_cast(unsigned, f);
    u += 0x7FFFu + ((u >> 16) & 1u);   // round-to-nearest-even
    return (u16)(u >> 16);
}

// ---------------- embedding gather ----------------
__global__ void k_embed(const int* __restrict__ tok, const float* __restrict__ emb,
                        float* __restrict__ x) {
    int r = blockIdx.x;
    int t = tok[r];
    const float* src = emb + (size_t)t * DM;
    float* dst = x + (size_t)r * DM;
    for (int i = threadIdx.x; i < DM; i += 256) dst[i] = src[i];
}

// ---------------- RMSNorm -> bf16 ----------------
__global__ __launch_bounds__(256)
void k_rmsnorm_bf16(const float* __restrict__ x, const float* __restrict__ w,
                    u16* __restrict__ out) {
    int r = blockIdx.x;
    const float* row = x + (size_t)r * DM;
    int c0 = threadIdx.x * 3;
    float v[3]; float ss = 0.f;
#pragma unroll
    for (int i = 0; i < 3; ++i) { v[i] = row[c0 + i]; ss += v[i] * v[i]; }
#pragma unroll
    for (int o = 32; o > 0; o >>= 1) ss += __shfl_down(ss, o);
    __shared__ float s[4];
    int lane = threadIdx.x & 63, wv = threadIdx.x >> 6;
    if (lane == 0) s[wv] = ss;
    __syncthreads();
    float sc = rsqrtf((s[0] + s[1] + s[2] + s[3]) / (float)DM + EPSR);
#pragma unroll
    for (int i = 0; i < 3; ++i)
        out[(size_t)r * DM + c0 + i] = f2bf(v[i] * sc * w[c0 + i]);
}

// ---------------- f32 -> bf16 with 2D pad, 4 elems/thread (dc % 4 == 0) ----------------
__global__ void k_cvt_pad4(const float* __restrict__ src, u16* __restrict__ dst,
                           int sr, int sc, int sld, int dc, long total4) {
    long i4 = (long)blockIdx.x * 256 + threadIdx.x;
    if (i4 >= total4) return;
    long i = i4 * 4;
    int r = (int)(i / dc), c0 = (int)(i % dc);
    us4 o;
#pragma unroll
    for (int e = 0; e < 4; ++e) {
        int c = c0 + e;
        float v = (r < sr && c < sc) ? src[(size_t)r * sld + c] : 0.f;
        o[e] = f2bf(v);
    }
    *(us4*)&dst[i] = o;
}

// ---------------- causal depthwise conv (width 4) + bias + silu ----------------
__global__ void k_conv_silu(const float* __restrict__ xz, const float* __restrict__ cw,
                            const float* __restrict__ cb, float* __restrict__ uc,
                            u16* __restrict__ ucb) {
    int d = blockIdx.x * 256 + threadIdx.x;   // 0..1535
    int r = blockIdx.y;                       // 0..2047
    int l = r & (SL - 1);
    float acc = cb[d];
#pragma unroll
    for (int j = 0; j < 4; ++j) {
        int ls = l - 3 + j;
        if (ls >= 0) acc += xz[(size_t)(r - 3 + j) * (2 * DI) + d] * cw[d * 4 + j];
    }
    float s = acc / (1.f + __expf(-acc));
    uc[(size_t)r * DI + d] = s;
    ucb[(size_t)r * DI + d] = f2bf(s);
}

// ---------------- softplus(dt + b) ----------------
__global__ void k_softplus(const float* __restrict__ in, const float* __restrict__ b,
                           float* __restrict__ out) {
    int i = blockIdx.x * 256 + threadIdx.x;   // 2048*1536
    int d = i % DI;
    float v = in[i] + b[d];
    out[i] = (v > 20.f) ? v : log1pf(__expf(v));
}

// ---------------- chunked selective scan (8 chunks x 128 steps, 1 kernel) --------------
// block = 512 thr = 8 waves; wave w owns chunk w of 128 timesteps for 16 channels.
// lane: ch = lane>>2 (channel), nq = lane&3; lane carries states n = nq+4k, k=0..3.
// Phase 1: per-chunk local scan (h0=0) -> S (final h), P = exp(A * sum(delta)).
// Phase 2: LDS sequential combine over 8 chunks -> per-chunk initial states.
// Phase 3: rescan with true h0, reduce over n (in-lane 4 + 2 shfl), gate, store bf16.
__global__ __launch_bounds__(512)
void k_scan2(const float* __restrict__ delta, const float* __restrict__ uc,
             const float* __restrict__ xdbl, const float* __restrict__ xz,
             const float* __restrict__ alog, const float* __restrict__ Dp,
             u16* __restrict__ ybf) {
    __shared__ float ds2[8][16][20], us2[8][16][20], bn2[8][16][20], cn2[8][16][20];
    __shared__ float Sm[8][16][16], Pm[8][16][16];
    int b  = blockIdx.x / 96;
    int d0 = (blockIdx.x % 96) * 16;
    int tid = threadIdx.x, w = tid >> 6, lane = tid & 63;
    int ch = lane >> 2, nq = lane & 3;
    int d = d0 + ch;
    float A[4];
#pragma unroll
    for (int k = 0; k < 4; ++k) A[k] = -__expf(alog[d * DSN + nq + 4 * k]);
    int tb = w * 128;

    // ---- phase 1 ----
    float h[4] = {0.f, 0.f, 0.f, 0.f};
    float sdl = 0.f;
    for (int t0 = 0; t0 < 128; t0 += 16) {
        int row0 = b * SL + tb + t0;
#pragma unroll
        for (int i = 0; i < 4; ++i) {
            int lin = i * 64 + lane, tt = lin >> 4, cc = lin & 15;
            size_t row = (size_t)(row0 + tt);
            ds2[w][cc][tt] = delta[row * DI + d0 + cc];
            us2[w][cc][tt] = uc[row * DI + d0 + cc];
            bn2[w][cc][tt] = xdbl[row * 128 + 48 + cc];
        }
#pragma unroll
        for (int g4 = 0; g4 < 4; ++g4) {
            f32x4 dl = *(const f32x4*)&ds2[w][ch][g4 * 4];
            f32x4 uv = *(const f32x4*)&us2[w][ch][g4 * 4];
            f32x4 bv[4];
#pragma unroll
            for (int k = 0; k < 4; ++k) bv[k] = *(const f32x4*)&bn2[w][nq + 4 * k][g4 * 4];
#pragma unroll
            for (int s = 0; s < 4; ++s) {
                float du = dl[s] * uv[s];
                sdl += dl[s];
#pragma unroll
                for (int k = 0; k < 4; ++k) {
                    float dA = __expf(dl[s] * A[k]);
                    h[k] = h[k] * dA + du * bv[k][s];
                }
            }
        }
    }
#pragma unroll
    for (int k = 0; k < 4; ++k) {
        Sm[w][ch][nq + 4 * k] = h[k];
        Pm[w][ch][nq + 4 * k] = __expf(A[k] * sdl);   // prod of dA over chunk, exactly
    }
    __syncthreads();
    // ---- phase 2: sequential chunk combine; Sm[g] becomes chunk-g INITIAL state ----
    if (tid < 256) {
        int c2 = tid >> 4, n2 = tid & 15;
        float H = 0.f;
#pragma unroll
        for (int g = 0; g < 8; ++g) {
            float hi = H;
            H = Pm[g][c2][n2] * H + Sm[g][c2][n2];
            Sm[g][c2][n2] = hi;
        }
    }
    __syncthreads();
    // ---- phase 3 ----
    float Dv = Dp[d];
#pragma unroll
    for (int k = 0; k < 4; ++k) h[k] = Sm[w][ch][nq + 4 * k];
    for (int t0 = 0; t0 < 128; t0 += 16) {
        int row0 = b * SL + tb + t0;
#pragma unroll
        for (int i = 0; i < 4; ++i) {
            int lin = i * 64 + lane, tt = lin >> 4, cc = lin & 15;
            size_t row = (size_t)(row0 + tt);
            ds2[w][cc][tt] = delta[row * DI + d0 + cc];
            us2[w][cc][tt] = uc[row * DI + d0 + cc];
            bn2[w][cc][tt] = xdbl[row * 128 + 48 + cc];
            cn2[w][cc][tt] = xdbl[row * 128 + 64 + cc];
        }
#pragma unroll
        for (int g4 = 0; g4 < 4; ++g4) {
            f32x4 dl = *(const f32x4*)&ds2[w][ch][g4 * 4];
            f32x4 uv = *(const f32x4*)&us2[w][ch][g4 * 4];
            f32x4 bv[4], cv[4];
#pragma unroll
            for (int k = 0; k < 4; ++k) {
                bv[k] = *(const f32x4*)&bn2[w][nq + 4 * k][g4 * 4];
                cv[k] = *(const f32x4*)&cn2[w][nq + 4 * k][g4 * 4];
            }
#pragma unroll
            for (int s = 0; s < 4; ++s) {
                float du = dl[s] * uv[s];
                float p = 0.f;
#pragma unroll
                for (int k = 0; k < 4; ++k) {
                    float dA = __expf(dl[s] * A[k]);
                    h[k] = h[k] * dA + du * bv[k][s];
                    p += h[k] * cv[k][s];
                }
                p += __shfl_xor(p, 1);
                p += __shfl_xor(p, 2);
                if (nq == 0) {
                    size_t row = (size_t)(row0 + g4 * 4 + s);
                    float z = xz[row * (2 * DI) + DI + d];
                    float y = p + uv[s] * Dv;
                    y *= z / (1.f + __expf(-z));
                    ybf[row * DI + d] = f2bf(y);
                }
            }
        }
    }
}

// ---------------- bf16 MFMA GEMM: C[M,N](f32) = A[M,K](bf16) @ W[N,K]^T(bf16) ----------
// 128x128 tile, BK=32, 4 waves. global_load_lds w16 staging with pre-swizzled SOURCE
// k-offset; fragment reads use matching XOR swizzle -> 2-way (free) LDS bank aliasing.
// Flat 1D grid, m-tile-fastest + bijective XCD chunk swizzle for W-panel L2 reuse.
template <bool ADD_RES, bool NGUARD>
__global__ __launch_bounds__(256)
void k_gemm_bt(const u16* __restrict__ A, const u16* __restrict__ W,
               float* __restrict__ C, const float* __restrict__ RES,
               int K, int ldc, int nmax, int nTm) {
    __shared__ u16 Al[128 * 32];
    __shared__ u16 Wl[128 * 32];
    // bijective XCD swizzle (m204) then m-fastest decode
    int nwg = gridDim.x;
    int qc = nwg >> 3, rc = nwg & 7;
    int xcd = blockIdx.x & 7, j = blockIdx.x >> 3;
    int wg = (xcd < rc ? xcd * (qc + 1) : rc * (qc + 1) + (xcd - rc) * qc) + j;
    int m0 = (wg % nTm) * 128, n0 = (wg / nTm) * 128;

    int tid = threadIdx.x, wave = tid >> 6, lane = tid & 63;
    int wm = wave >> 1, wn = wave & 1;
    f32x4 acc[4][4] = {};
    const int rS = (lane >> 2);                                   // staging row in 16-chunk
    const int kS = (((lane & 3) ^ ((lane >> 3) & 3)) * 8);        // pre-swizzled source k
    const int kofs = (((lane >> 4) ^ ((lane >> 1) & 3)) * 8);     // swizzled fragment k
    const int fr = lane & 15;

    for (int k0 = 0; k0 < K; k0 += 32) {
#pragma unroll
        for (int i = 0; i < 2; ++i) {
            int rowA = m0 + wave * 32 + i * 16 + rS;
            const u16* ga = A + (size_t)rowA * K + k0 + kS;
            __builtin_amdgcn_global_load_lds(
                (const __attribute__((address_space(1))) void*)ga,
                (__attribute__((address_space(3))) void*)(&Al[wave * 1024 + i * 512]),
                16, 0, 0);
            int rowW = n0 + wave * 32 + i * 16 + rS;
            const u16* gw = W + (size_t)rowW * K + k0 + kS;
            __builtin_amdgcn_global_load_lds(
                (const __attribute__((address_space(1))) void*)gw,
                (__attribute__((address_space(3))) void*)(&Wl[wave * 1024 + i * 512]),
                16, 0, 0);
        }
        __syncthreads();
        short8 af[4], bfr[4];
#pragma unroll
        for (int f = 0; f < 4; ++f) {
            af[f]  = *(const short8*)&Al[(wm * 64 + f * 16 + fr) * 32 + kofs];
            bfr[f] = *(const short8*)&Wl[(wn * 64 + f * 16 + fr) * 32 + kofs];
        }
#pragma unroll
        for (int i = 0; i < 4; ++i)
#pragma unroll
            for (int jj = 0; jj < 4; ++jj)
                acc[i][jj] = __builtin_amdgcn_mfma_f32_16x16x32_bf16(af[i], bfr[jj], acc[i][jj], 0, 0, 0);
        __syncthreads();
    }
    int r4 = (lane >> 4) * 4;
#pragma unroll
    for (int i = 0; i < 4; ++i)
#pragma unroll
        for (int jj = 0; jj < 4; ++jj) {
            int col = n0 + wn * 64 + jj * 16 + fr;
            if (NGUARD && col >= nmax) continue;
#pragma unroll
            for (int rr = 0; rr < 4; ++rr) {
                int row = m0 + wm * 64 + i * 16 + r4 + rr;
                size_t off = (size_t)row * ldc + col;
                float v = acc[i][jj][rr];
                if (ADD_RES) v += RES[off];
                C[off] = v;
            }
        }
}

// ---------------- host ----------------
extern "C" void kernel_launch(void* const* d_in, const int* in_sizes, int n_in,
                              void* d_out, int out_size, void* d_ws, size_t ws_size,
                              hipStream_t stream) {
    (void)in_sizes; (void)n_in; (void)out_size;
    const int*   tok   = (const int*)d_in[0];
    const float* emb   = (const float*)d_in[1];
    const float* normw = (const float*)d_in[2];
    const float* inw   = (const float*)d_in[3];
    const float* cw    = (const float*)d_in[4];
    const float* cb    = (const float*)d_in[5];
    const float* xpw   = (const float*)d_in[6];
    const float* dtw   = (const float*)d_in[7];
    const float* dtb   = (const float*)d_in[8];
    const float* alog  = (const float*)d_in[9];
    const float* Dp    = (const float*)d_in[10];
    const float* outw  = (const float*)d_in[11];
    const float* normf = (const float*)d_in[12];
    const float* lmw   = (const float*)d_in[13];
    float* out = (float*)d_out;

    char* p = (char*)d_ws;
    auto alloc = [&](size_t bytes) { char* r = p; p += (bytes + 255) & ~(size_t)255; return r; };
    float* x     = (float*)alloc((size_t)MROWS * DM * 4);
    u16*   xnb   = (u16*)  alloc((size_t)MROWS * DM * 2);
    float* xz    = (float*)alloc((size_t)MROWS * 2 * DI * 4);
    float* uc    = (float*)alloc((size_t)MROWS * DI * 4);
    u16*   ucb   = (u16*)  alloc((size_t)MROWS * DI * 2);
    float* xdbl  = (float*)alloc((size_t)MROWS * 128 * 4);
    u16*   xdblb = (u16*)  alloc((size_t)MROWS * 64 * 2);
    float* dtraw = (float*)alloc((size_t)MROWS * DI * 4);
    float* delta = (float*)alloc((size_t)MROWS * DI * 4);
    u16*   ybf   = (u16*)  alloc((size_t)MROWS * DI * 2);
    u16*   winb  = (u16*)  alloc((size_t)(2 * DI) * DM * 2);
    u16*   wxpb  = (u16*)  alloc((size_t)128 * DI * 2);
    u16*   wdtb  = (u16*)  alloc((size_t)DI * 64 * 2);
    u16*   woutb = (u16*)  alloc((size_t)DM * DI * 2);
    u16*   wlmb  = (u16*)  alloc((size_t)VOCP * DM * 2);
    if ((size_t)(p - (char*)d_ws) > ws_size) return;  // insufficient scratch: fail loudly

    // lm_head weight -> bf16, padded to 50304 rows
    {
        long t4 = (long)VOCP * DM / 4;
        k_cvt_pad4<<<dim3((unsigned)((t4 + 255) / 256)), 256, 0, stream>>>(
            lmw, wlmb, VOC, DM, DM, DM, t4);
    }

    k_embed<<<MROWS, 256, 0, stream>>>(tok, emb, x);

    for (int i = 0; i < NB; ++i) {
        k_rmsnorm_bf16<<<MROWS, 256, 0, stream>>>(x, normw + i * DM, xnb);

        { long t4 = (long)(2 * DI) * DM / 4;
          k_cvt_pad4<<<dim3((unsigned)((t4 + 255) / 256)), 256, 0, stream>>>(
              inw + (size_t)i * 2 * DI * DM, winb, 2 * DI, DM, DM, DM, t4); }
        k_gemm_bt<false, false><<<dim3(16 * (2 * DI / 128)), 256, 0, stream>>>(
            xnb, winb, xz, nullptr, DM, 2 * DI, 2 * DI, 16);

        k_conv_silu<<<dim3(DI / 256, MROWS), 256, 0, stream>>>(
            xz, cw + (size_t)i * DI * 4, cb + (size_t)i * DI, uc, ucb);

        { long t4 = (long)128 * DI / 4;
          k_cvt_pad4<<<dim3((unsigned)((t4 + 255) / 256)), 256, 0, stream>>>(
              xpw + (size_t)i * 80 * DI, wxpb, 80, DI, DI, DI, t4); }
        k_gemm_bt<false, false><<<dim3(16 * 1), 256, 0, stream>>>(
            ucb, wxpb, xdbl, nullptr, DI, 128, 128, 16);

        { long t4 = (long)MROWS * 64 / 4;
          k_cvt_pad4<<<dim3((unsigned)((t4 + 255) / 256)), 256, 0, stream>>>(
              xdbl, xdblb, MROWS, 64, 128, 64, t4); }
        { long t4 = (long)DI * 64 / 4;
          k_cvt_pad4<<<dim3((unsigned)((t4 + 255) / 256)), 256, 0, stream>>>(
              dtw + (size_t)i * DI * 48, wdtb, DI, 48, 48, 64, t4); }
        k_gemm_bt<false, false><<<dim3(16 * (DI / 128)), 256, 0, stream>>>(
            xdblb, wdtb, dtraw, nullptr, 64, DI, DI, 16);

        k_softplus<<<dim3(MROWS * DI / 256), 256, 0, stream>>>(dtraw, dtb + i * DI, delta);

        k_scan2<<<dim3(NB * (DI / 16)), 512, 0, stream>>>(
            delta, uc, xdbl, xz, alog + (size_t)i * DI * DSN, Dp + i * DI, ybf);

        { long t4 = (long)DM * DI / 4;
          k_cvt_pad4<<<dim3((unsigned)((t4 + 255) / 256)), 256, 0, stream>>>(
              outw + (size_t)i * DM * DI, woutb, DM, DI, DI, DI, t4); }
        k_gemm_bt<true, false><<<dim3(16 * (DM / 128)), 256, 0, stream>>>(
            ybf, woutb, x, x, DI, DM, DM, 16);
    }

    k_rmsnorm_bf16<<<MROWS, 256, 0, stream>>>(x, normf, xnb);
    k_gemm_bt<false, true><<<dim3(16 * (VOCP / 128)), 256, 0, stream>>>(
        xnb, wlmb, out, nullptr, DM, VOC, VOC, 16);
}

// Round 6
// 770.574 us; speedup vs baseline: 1.6257x; 1.0874x over previous
//
#include <hip/hip_runtime.h>
#include <hip/hip_bf16.h>
#include <math.h>

#define DM 768
#define DI 1536
#define DSN 16
#define NB 2
#define SL 1024
#define MROWS 2048
#define VOC 50257
#define VOCP 50432           // padded to multiple of 256 for the 256^2 lm_head GEMM
#define EPSR 1e-5f

typedef __attribute__((ext_vector_type(8))) short short8;
typedef __attribute__((ext_vector_type(4))) float f32x4;
typedef __attribute__((ext_vector_type(4))) unsigned short us4;
typedef unsigned short u16;

__device__ inline u16 f2bf(float f) {
    unsigned u = __builtin_bit_cast(unsigned, f);
    u += 0x7FFFu + ((u >> 16) & 1u);   // round-to-nearest-even
    return (u16)(u >> 16);
}

// ---------------- embedding gather ----------------
__global__ void k_embed(const int* __restrict__ tok, const float* __restrict__ emb,
                        float* __restrict__ x) {
    int r = blockIdx.x;
    int t = tok[r];
    const float* src = emb + (size_t)t * DM;
    float* dst = x + (size_t)r * DM;
    for (int i = threadIdx.x; i < DM; i += 256) dst[i] = src[i];
}

// ---------------- RMSNorm -> bf16 ----------------
__global__ __launch_bounds__(256)
void k_rmsnorm_bf16(const float* __restrict__ x, const float* __restrict__ w,
                    u16* __restrict__ out) {
    int r = blockIdx.x;
    const float* row = x + (size_t)r * DM;
    int c0 = threadIdx.x * 3;
    float v[3]; float ss = 0.f;
#pragma unroll
    for (int i = 0; i < 3; ++i) { v[i] = row[c0 + i]; ss += v[i] * v[i]; }
#pragma unroll
    for (int o = 32; o > 0; o >>= 1) ss += __shfl_down(ss, o);
    __shared__ float s[4];
    int lane = threadIdx.x & 63, wv = threadIdx.x >> 6;
    if (lane == 0) s[wv] = ss;
    __syncthreads();
    float sc = rsqrtf((s[0] + s[1] + s[2] + s[3]) / (float)DM + EPSR);
#pragma unroll
    for (int i = 0; i < 3; ++i)
        out[(size_t)r * DM + c0 + i] = f2bf(v[i] * sc * w[c0 + i]);
}

// ---------------- f32 -> bf16 with 2D pad, 4 elems/thread (dc % 4 == 0) ----------------
__global__ void k_cvt_pad4(const float* __restrict__ src, u16* __restrict__ dst,
                           int sr, int sc, int sld, int dc, long total4) {
    long i4 = (long)blockIdx.x * 256 + threadIdx.x;
    if (i4 >= total4) return;
    long i = i4 * 4;
    int r = (int)(i / dc), c0 = (int)(i % dc);
    us4 o;
#pragma unroll
    for (int e = 0; e < 4; ++e) {
        int c = c0 + e;
        float v = (r < sr && c < sc) ? src[(size_t)r * sld + c] : 0.f;
        o[e] = f2bf(v);
    }
    *(us4*)&dst[i] = o;
}

// ---------------- causal depthwise conv (width 4) + bias + silu ----------------
__global__ void k_conv_silu(const float* __restrict__ xz, const float* __restrict__ cw,
                            const float* __restrict__ cb, float* __restrict__ uc,
                            u16* __restrict__ ucb) {
    int d = blockIdx.x * 256 + threadIdx.x;   // 0..1535
    int r = blockIdx.y;                       // 0..2047
    int l = r & (SL - 1);
    float acc = cb[d];
#pragma unroll
    for (int j = 0; j < 4; ++j) {
        int ls = l - 3 + j;
        if (ls >= 0) acc += xz[(size_t)(r - 3 + j) * (2 * DI) + d] * cw[d * 4 + j];
    }
    float s = acc / (1.f + __expf(-acc));
    uc[(size_t)r * DI + d] = s;
    ucb[(size_t)r * DI + d] = f2bf(s);
}

// ---------------- softplus(dt + b) ----------------
__global__ void k_softplus(const float* __restrict__ in, const float* __restrict__ b,
                           float* __restrict__ out) {
    int i = blockIdx.x * 256 + threadIdx.x;   // 2048*1536
    int d = i % DI;
    float v = in[i] + b[d];
    out[i] = (v > 20.f) ? v : log1pf(__expf(v));
}

// ---------------- chunked selective scan (8 chunks x 128 steps, 1 kernel) --------------
__global__ __launch_bounds__(512)
void k_scan2(const float* __restrict__ delta, const float* __restrict__ uc,
             const float* __restrict__ xdbl, const float* __restrict__ xz,
             const float* __restrict__ alog, const float* __restrict__ Dp,
             u16* __restrict__ ybf) {
    __shared__ float ds2[8][16][20], us2[8][16][20], bn2[8][16][20], cn2[8][16][20];
    __shared__ float Sm[8][16][16], Pm[8][16][16];
    int b  = blockIdx.x / 96;
    int d0 = (blockIdx.x % 96) * 16;
    int tid = threadIdx.x, w = tid >> 6, lane = tid & 63;
    int ch = lane >> 2, nq = lane & 3;
    int d = d0 + ch;
    float A[4];
#pragma unroll
    for (int k = 0; k < 4; ++k) A[k] = -__expf(alog[d * DSN + nq + 4 * k]);
    int tb = w * 128;

    // ---- phase 1 ----
    float h[4] = {0.f, 0.f, 0.f, 0.f};
    float sdl = 0.f;
    for (int t0 = 0; t0 < 128; t0 += 16) {
        int row0 = b * SL + tb + t0;
#pragma unroll
        for (int i = 0; i < 4; ++i) {
            int lin = i * 64 + lane, tt = lin >> 4, cc = lin & 15;
            size_t row = (size_t)(row0 + tt);
            ds2[w][cc][tt] = delta[row * DI + d0 + cc];
            us2[w][cc][tt] = uc[row * DI + d0 + cc];
            bn2[w][cc][tt] = xdbl[row * 128 + 48 + cc];
        }
#pragma unroll
        for (int g4 = 0; g4 < 4; ++g4) {
            f32x4 dl = *(const f32x4*)&ds2[w][ch][g4 * 4];
            f32x4 uv = *(const f32x4*)&us2[w][ch][g4 * 4];
            f32x4 bv[4];
#pragma unroll
            for (int k = 0; k < 4; ++k) bv[k] = *(const f32x4*)&bn2[w][nq + 4 * k][g4 * 4];
#pragma unroll
            for (int s = 0; s < 4; ++s) {
                float du = dl[s] * uv[s];
                sdl += dl[s];
#pragma unroll
                for (int k = 0; k < 4; ++k) {
                    float dA = __expf(dl[s] * A[k]);
                    h[k] = h[k] * dA + du * bv[k][s];
                }
            }
        }
    }
#pragma unroll
    for (int k = 0; k < 4; ++k) {
        Sm[w][ch][nq + 4 * k] = h[k];
        Pm[w][ch][nq + 4 * k] = __expf(A[k] * sdl);
    }
    __syncthreads();
    if (tid < 256) {
        int c2 = tid >> 4, n2 = tid & 15;
        float H = 0.f;
#pragma unroll
        for (int g = 0; g < 8; ++g) {
            float hi = H;
            H = Pm[g][c2][n2] * H + Sm[g][c2][n2];
            Sm[g][c2][n2] = hi;
        }
    }
    __syncthreads();
    // ---- phase 3 ----
    float Dv = Dp[d];
#pragma unroll
    for (int k = 0; k < 4; ++k) h[k] = Sm[w][ch][nq + 4 * k];
    for (int t0 = 0; t0 < 128; t0 += 16) {
        int row0 = b * SL + tb + t0;
#pragma unroll
        for (int i = 0; i < 4; ++i) {
            int lin = i * 64 + lane, tt = lin >> 4, cc = lin & 15;
            size_t row = (size_t)(row0 + tt);
            ds2[w][cc][tt] = delta[row * DI + d0 + cc];
            us2[w][cc][tt] = uc[row * DI + d0 + cc];
            bn2[w][cc][tt] = xdbl[row * 128 + 48 + cc];
            cn2[w][cc][tt] = xdbl[row * 128 + 64 + cc];
        }
#pragma unroll
        for (int g4 = 0; g4 < 4; ++g4) {
            f32x4 dl = *(const f32x4*)&ds2[w][ch][g4 * 4];
            f32x4 uv = *(const f32x4*)&us2[w][ch][g4 * 4];
            f32x4 bv[4], cv[4];
#pragma unroll
            for (int k = 0; k < 4; ++k) {
                bv[k] = *(const f32x4*)&bn2[w][nq + 4 * k][g4 * 4];
                cv[k] = *(const f32x4*)&cn2[w][nq + 4 * k][g4 * 4];
            }
#pragma unroll
            for (int s = 0; s < 4; ++s) {
                float du = dl[s] * uv[s];
                float p = 0.f;
#pragma unroll
                for (int k = 0; k < 4; ++k) {
                    float dA = __expf(dl[s] * A[k]);
                    h[k] = h[k] * dA + du * bv[k][s];
                    p += h[k] * cv[k][s];
                }
                p += __shfl_xor(p, 1);
                p += __shfl_xor(p, 2);
                if (nq == 0) {
                    size_t row = (size_t)(row0 + g4 * 4 + s);
                    float z = xz[row * (2 * DI) + DI + d];
                    float y = p + uv[s] * Dv;
                    y *= z / (1.f + __expf(-z));
                    ybf[row * DI + d] = f2bf(y);
                }
            }
        }
    }
}

// ---------------- 128^2 bf16 MFMA GEMM (kept for the small/medium GEMMs) --------------
template <bool ADD_RES, bool NGUARD>
__global__ __launch_bounds__(256)
void k_gemm_bt(const u16* __restrict__ A, const u16* __restrict__ W,
               float* __restrict__ C, const float* __restrict__ RES,
               int K, int ldc, int nmax, int nTm) {
    __shared__ u16 Al[128 * 32];
    __shared__ u16 Wl[128 * 32];
    int nwg = gridDim.x;
    int qc = nwg >> 3, rc = nwg & 7;
    int xcd = blockIdx.x & 7, j = blockIdx.x >> 3;
    int wg = (xcd < rc ? xcd * (qc + 1) : rc * (qc + 1) + (xcd - rc) * qc) + j;
    int m0 = (wg % nTm) * 128, n0 = (wg / nTm) * 128;

    int tid = threadIdx.x, wave = tid >> 6, lane = tid & 63;
    int wm = wave >> 1, wn = wave & 1;
    f32x4 acc[4][4] = {};
    const int rS = (lane >> 2);
    const int kS = (((lane & 3) ^ ((lane >> 3) & 3)) * 8);
    const int kofs = (((lane >> 4) ^ ((lane >> 1) & 3)) * 8);
    const int fr = lane & 15;

    for (int k0 = 0; k0 < K; k0 += 32) {
#pragma unroll
        for (int i = 0; i < 2; ++i) {
            int rowA = m0 + wave * 32 + i * 16 + rS;
            const u16* ga = A + (size_t)rowA * K + k0 + kS;
            __builtin_amdgcn_global_load_lds(
                (const __attribute__((address_space(1))) void*)ga,
                (__attribute__((address_space(3))) void*)(&Al[wave * 1024 + i * 512]),
                16, 0, 0);
            int rowW = n0 + wave * 32 + i * 16 + rS;
            const u16* gw = W + (size_t)rowW * K + k0 + kS;
            __builtin_amdgcn_global_load_lds(
                (const __attribute__((address_space(1))) void*)gw,
                (__attribute__((address_space(3))) void*)(&Wl[wave * 1024 + i * 512]),
                16, 0, 0);
        }
        __syncthreads();
        short8 af[4], bfr[4];
#pragma unroll
        for (int f = 0; f < 4; ++f) {
            af[f]  = *(const short8*)&Al[(wm * 64 + f * 16 + fr) * 32 + kofs];
            bfr[f] = *(const short8*)&Wl[(wn * 64 + f * 16 + fr) * 32 + kofs];
        }
#pragma unroll
        for (int i = 0; i < 4; ++i)
#pragma unroll
            for (int jj = 0; jj < 4; ++jj)
                acc[i][jj] = __builtin_amdgcn_mfma_f32_16x16x32_bf16(af[i], bfr[jj], acc[i][jj], 0, 0, 0);
        __syncthreads();
    }
    int r4 = (lane >> 4) * 4;
#pragma unroll
    for (int i = 0; i < 4; ++i)
#pragma unroll
        for (int jj = 0; jj < 4; ++jj) {
            int col = n0 + wn * 64 + jj * 16 + fr;
            if (NGUARD && col >= nmax) continue;
#pragma unroll
            for (int rr = 0; rr < 4; ++rr) {
                int row = m0 + wm * 64 + i * 16 + r4 + rr;
                size_t off = (size_t)row * ldc + col;
                float v = acc[i][jj][rr];
                if (ADD_RES) v += RES[off];
                C[off] = v;
            }
        }
}

// ============ 256^2 8-phase bf16 GEMM (lm_head): C = A[M,K] @ W[N,K]^T ============
// 512 thr = 8 waves (2M x 4N); per-wave 128x64 out; BK=64; LDS 128 KiB dbuf;
// st_16x32 swizzle (pre-swizzled gload source + swizzled ds_read); counted vmcnt(6).
#define G_LDS16(g, l) __builtin_amdgcn_global_load_lds( \
    (const __attribute__((address_space(1))) void*)(g), \
    (__attribute__((address_space(3))) void*)(l), 16, 0, 0)
#define BAR  __builtin_amdgcn_s_barrier()
#define LGK0 do { asm volatile("s_waitcnt lgkmcnt(0)" ::: "memory"); \
                  __builtin_amdgcn_sched_barrier(0); } while (0)
#define VMC6 asm volatile("s_waitcnt vmcnt(6)" ::: "memory")
#define VMC0 asm volatile("s_waitcnt vmcnt(0)" ::: "memory")

// stage half-tile (t, op, half): 16 KB; each wave 2x global_load_lds of 1 KB
#define STAGE_HT(t, op, half, GB, RB) do {                                   \
    const u16* _g = (GB) + (size_t)((RB) + (half) * 128 + (w << 3) + srow) * K \
                    + (t) * 64 + scol;                                        \
    G_LDS16(_g, &lds[(t) & 1][op][half][w << 9]);                             \
    G_LDS16(_g + (size_t)64 * K, &lds[(t) & 1][op][half][4096 + (w << 9)]);   \
} while (0)

#define RD_A(dst, t, mq) do {                                                \
    _Pragma("unroll") for (int _m = 0; _m < 4; ++_m)                          \
    _Pragma("unroll") for (int _k = 0; _k < 2; ++_k)                          \
        dst[_m][_k] = *(const short8*)&lds[(t) & 1][0][wm]                    \
            [(mq) * 4096 + _m * 1024 + _k * 32 + rd_off];                     \
} while (0)

#define RD_B(t, nq) do {                                                     \
    _Pragma("unroll") for (int _n = 0; _n < 2; ++_n)                          \
    _Pragma("unroll") for (int _k = 0; _k < 2; ++_k)                          \
        bfv[_n][_k] = *(const short8*)&lds[(t) & 1][1][wbh]                   \
            [wbr * 4096 + (nq) * 2048 + _n * 1024 + _k * 32 + rd_off];        \
} while (0)

#define MM16(AF, mq, nq) do {                                                \
    __builtin_amdgcn_s_setprio(1);                                           \
    _Pragma("unroll") for (int _m = 0; _m < 4; ++_m)                          \
    _Pragma("unroll") for (int _n = 0; _n < 2; ++_n)                          \
    _Pragma("unroll") for (int _k = 0; _k < 2; ++_k)                          \
        acc[(mq) * 4 + _m][(nq) * 2 + _n] =                                   \
            __builtin_amdgcn_mfma_f32_16x16x32_bf16(                          \
                AF[_m][_k], bfv[_n][_k], acc[(mq) * 4 + _m][(nq) * 2 + _n],   \
                0, 0, 0);                                                     \
    __builtin_amdgcn_s_setprio(0);                                           \
} while (0)

template <int K>
__global__ __launch_bounds__(512, 2)
void k_gemm256(const u16* __restrict__ Ap, const u16* __restrict__ Wp,
               float* __restrict__ C, int ldc, int nmax, int nTm) {
    constexpr int NT = K / 64;       // K-tiles (must be even, >= 4)
    constexpr int NI = NT / 2;       // pair iterations
    __shared__ __align__(16) u16 lds[2][2][2][8192];  // [buf][A/B][half][128x64]

    int per8 = gridDim.x >> 3;
    int wg = (blockIdx.x & 7) * per8 + (blockIdx.x >> 3);
    int m0 = (wg % nTm) * 256, n0 = (wg / nTm) * 256;

    int tid = threadIdx.x, w = tid >> 6, lane = tid & 63;
    int wm = w >> 2, wn = w & 3, wbh = wn >> 1, wbr = wn & 1;
    int fr = lane & 15;
    // swizzled ds_read per-lane offset (u16 elems)
    int rd_off = fr * 64 + (((lane >> 4) * 8) ^ (((fr >> 2) & 1) * 16));
    // staging per-lane: row-in-chunk + pre-swizzled source k
    int srow = lane >> 3;
    int scol = ((lane & 7) * 8) ^ (((lane >> 5) & 1) * 16);

    f32x4 acc[8][4] = {};
    short8 af0[4][2], af1[4][2], bfv[2][2];

    // ---- prologue: tile0 full + tile1 {A0,A1,B0}; 14 loads/wave; vmcnt(6) => tile0 ----
    STAGE_HT(0, 0, 0, Ap, m0); STAGE_HT(0, 0, 1, Ap, m0);
    STAGE_HT(0, 1, 0, Wp, n0); STAGE_HT(0, 1, 1, Wp, n0);
    STAGE_HT(1, 0, 0, Ap, m0); STAGE_HT(1, 0, 1, Ap, m0);
    STAGE_HT(1, 1, 0, Wp, n0);
    VMC6; BAR;

    // ---- main loop: iterations 0..NI-2, fully staged, vmcnt(6) at phases 4 & 8 ----
    for (int i = 0; i < NI - 1; ++i) {
        const int ta = 2 * i, tb = 2 * i + 1;
        // P1
        RD_A(af0, ta, 0); RD_B(ta, 0);
        STAGE_HT(tb, 1, 1, Wp, n0);
        BAR; LGK0; MM16(af0, 0, 0); BAR;
        // P2
        RD_A(af1, ta, 1);
        STAGE_HT(ta + 2, 0, 0, Ap, m0);
        BAR; LGK0; MM16(af1, 1, 0); BAR;
        // P3
        RD_B(ta, 1);
        STAGE_HT(ta + 2, 0, 1, Ap, m0);
        BAR; LGK0; MM16(af1, 1, 1); BAR;
        // P4
        STAGE_HT(ta + 2, 1, 0, Wp, n0);
        BAR; MM16(af0, 0, 1); VMC6; BAR;
        // P5
        RD_A(af0, tb, 0); RD_B(tb, 0);
        STAGE_HT(ta + 2, 1, 1, Wp, n0);
        BAR; LGK0; MM16(af0, 0, 0); BAR;
        // P6
        RD_A(af1, tb, 1);
        STAGE_HT(ta + 3, 0, 0, Ap, m0);
        BAR; LGK0; MM16(af1, 1, 0); BAR;
        // P7
        RD_B(tb, 1);
        STAGE_HT(ta + 3, 0, 1, Ap, m0);
        BAR; LGK0; MM16(af1, 1, 1); BAR;
        // P8
        STAGE_HT(ta + 3, 1, 0, Wp, n0);
        BAR; MM16(af0, 0, 1); VMC6; BAR;
    }
    // ---- peeled last pair (tiles NT-2, NT-1): only P1 stages; vmcnt(0) at P4 ----
    {
        const int ta = NT - 2, tb = NT - 1;
        RD_A(af0, ta, 0); RD_B(ta, 0);
        STAGE_HT(tb, 1, 1, Wp, n0);
        BAR; LGK0; MM16(af0, 0, 0); BAR;
        RD_A(af1, ta, 1);
        BAR; LGK0; MM16(af1, 1, 0); BAR;
        RD_B(ta, 1);
        BAR; LGK0; MM16(af1, 1, 1); BAR;
        BAR; MM16(af0, 0, 1); VMC0; BAR;
        RD_A(af0, tb, 0); RD_B(tb, 0);
        BAR; LGK0; MM16(af0, 0, 0); BAR;
        RD_A(af1, tb, 1);
        BAR; LGK0; MM16(af1, 1, 0); BAR;
        RD_B(tb, 1);
        BAR; LGK0; MM16(af1, 1, 1); BAR;
        BAR; MM16(af0, 0, 1); BAR;
    }

    // ---- epilogue: C write (registers only) ----
    int r4 = (lane >> 4) * 4;
#pragma unroll
    for (int mi = 0; mi < 8; ++mi)
#pragma unroll
        for (int ni = 0; ni < 4; ++ni) {
            int col = n0 + wn * 64 + (ni >> 1) * 32 + (ni & 1) * 16 + fr;
            if (col >= nmax) continue;
            int row = m0 + wm * 128 + (mi >> 2) * 64 + (mi & 3) * 16 + r4;
#pragma unroll
            for (int rr = 0; rr < 4; ++rr)
                C[(size_t)(row + rr) * ldc + col] = acc[mi][ni][rr];
        }
}

// ---------------- host ----------------
extern "C" void kernel_launch(void* const* d_in, const int* in_sizes, int n_in,
                              void* d_out, int out_size, void* d_ws, size_t ws_size,
                              hipStream_t stream) {
    (void)in_sizes; (void)n_in; (void)out_size;
    const int*   tok   = (const int*)d_in[0];
    const float* emb   = (const float*)d_in[1];
    const float* normw = (const float*)d_in[2];
    const float* inw   = (const float*)d_in[3];
    const float* cw    = (const float*)d_in[4];
    const float* cb    = (const float*)d_in[5];
    const float* xpw   = (const float*)d_in[6];
    const float* dtw   = (const float*)d_in[7];
    const float* dtb   = (const float*)d_in[8];
    const float* alog  = (const float*)d_in[9];
    const float* Dp    = (const float*)d_in[10];
    const float* outw  = (const float*)d_in[11];
    const float* normf = (const float*)d_in[12];
    const float* lmw   = (const float*)d_in[13];
    float* out = (float*)d_out;

    char* p = (char*)d_ws;
    auto alloc = [&](size_t bytes) { char* r = p; p += (bytes + 255) & ~(size_t)255; return r; };
    float* x     = (float*)alloc((size_t)MROWS * DM * 4);
    u16*   xnb   = (u16*)  alloc((size_t)MROWS * DM * 2);
    float* xz    = (float*)alloc((size_t)MROWS * 2 * DI * 4);
    float* uc    = (float*)alloc((size_t)MROWS * DI * 4);
    u16*   ucb   = (u16*)  alloc((size_t)MROWS * DI * 2);
    float* xdbl  = (float*)alloc((size_t)MROWS * 128 * 4);
    u16*   xdblb = (u16*)  alloc((size_t)MROWS * 64 * 2);
    float* dtraw = (float*)alloc((size_t)MROWS * DI * 4);
    float* delta = (float*)alloc((size_t)MROWS * DI * 4);
    u16*   ybf   = (u16*)  alloc((size_t)MROWS * DI * 2);
    u16*   winb  = (u16*)  alloc((size_t)(2 * DI) * DM * 2);
    u16*   wxpb  = (u16*)  alloc((size_t)128 * DI * 2);
    u16*   wdtb  = (u16*)  alloc((size_t)DI * 64 * 2);
    u16*   woutb = (u16*)  alloc((size_t)DM * DI * 2);
    u16*   wlmb  = (u16*)  alloc((size_t)VOCP * DM * 2);
    if ((size_t)(p - (char*)d_ws) > ws_size) return;  // insufficient scratch: fail loudly

    // lm_head weight -> bf16, padded to VOCP rows
    {
        long t4 = (long)VOCP * DM / 4;
        k_cvt_pad4<<<dim3((unsigned)((t4 + 255) / 256)), 256, 0, stream>>>(
            lmw, wlmb, VOC, DM, DM, DM, t4);
    }

    k_embed<<<MROWS, 256, 0, stream>>>(tok, emb, x);

    for (int i = 0; i < NB; ++i) {
        k_rmsnorm_bf16<<<MROWS, 256, 0, stream>>>(x, normw + i * DM, xnb);

        { long t4 = (long)(2 * DI) * DM / 4;
          k_cvt_pad4<<<dim3((unsigned)((t4 + 255) / 256)), 256, 0, stream>>>(
              inw + (size_t)i * 2 * DI * DM, winb, 2 * DI, DM, DM, DM, t4); }
        k_gemm_bt<false, false><<<dim3(16 * (2 * DI / 128)), 256, 0, stream>>>(
            xnb, winb, xz, nullptr, DM, 2 * DI, 2 * DI, 16);

        k_conv_silu<<<dim3(DI / 256, MROWS), 256, 0, stream>>>(
            xz, cw + (size_t)i * DI * 4, cb + (size_t)i * DI, uc, ucb);

        { long t4 = (long)128 * DI / 4;
          k_cvt_pad4<<<dim3((unsigned)((t4 + 255) / 256)), 256, 0, stream>>>(
              xpw + (size_t)i * 80 * DI, wxpb, 80, DI, DI, DI, t4); }
        k_gemm_bt<false, false><<<dim3(16 * 1), 256, 0, stream>>>(
            ucb, wxpb, xdbl, nullptr, DI, 128, 128, 16);

        { long t4 = (long)MROWS * 64 / 4;
          k_cvt_pad4<<<dim3((unsigned)((t4 + 255) / 256)), 256, 0, stream>>>(
              xdbl, xdblb, MROWS, 64, 128, 64, t4); }
        { long t4 = (long)DI * 64 / 4;
          k_cvt_pad4<<<dim3((unsigned)((t4 + 255) / 256)), 256, 0, stream>>>(
              dtw + (size_t)i * DI * 48, wdtb, DI, 48, 48, 64, t4); }
        k_gemm_bt<false, false><<<dim3(16 * (DI / 128)), 256, 0, stream>>>(
            xdblb, wdtb, dtraw, nullptr, 64, DI, DI, 16);

        k_softplus<<<dim3(MROWS * DI / 256), 256, 0, stream>>>(dtraw, dtb + i * DI, delta);

        k_scan2<<<dim3(NB * (DI / 16)), 512, 0, stream>>>(
            delta, uc, xdbl, xz, alog + (size_t)i * DI * DSN, Dp + i * DI, ybf);

        { long t4 = (long)DM * DI / 4;
          k_cvt_pad4<<<dim3((unsigned)((t4 + 255) / 256)), 256, 0, stream>>>(
              outw + (size_t)i * DM * DI, woutb, DM, DI, DI, DI, t4); }
        k_gemm_bt<true, false><<<dim3(16 * (DM / 128)), 256, 0, stream>>>(
            ybf, woutb, x, x, DI, DM, DM, 16);
    }

    k_rmsnorm_bf16<<<MROWS, 256, 0, stream>>>(x, normf, xnb);
    // 256^2 8-phase GEMM for lm_head: grid = 8 m-tiles x 197 n-tiles
    k_gemm256<DM><<<dim3(8 * (VOCP / 256)), 512, 0, stream>>>(
        xnb, wlmb, out, VOC, VOC, 8);
}